// Round 5
// baseline (1629.629 us; speedup 1.0000x reference)
//
#include <hip/hip_runtime.h>
#include <hip/hip_fp16.h>

#define N_IJKL   1000000
#define N_UIJK   500000
#define N_IJK    250000
#define N_UIJKL  2000000
#define ROW_H    72        // halves per interleaved level row

// ---------------- tall-skinny GEMM: A[N,128] @ W[128,8] -> out[N,8] (f32 out) ----------------
__global__ __launch_bounds__(256) void k_gemm128x8(const float* __restrict__ A,
                                                   const float* __restrict__ W,
                                                   float* __restrict__ out) {
  __shared__ float sA[32][132];
  __shared__ float sW[8][132];
  const int t = threadIdx.x;
  for (int i = t; i < 1024; i += 256) sW[i & 7][i >> 3] = W[i];
  const long long r0 = (long long)blockIdx.x * 32;
  const float4* A4 = (const float4*)(A + r0 * 128);
  for (int i = t; i < 1024; i += 256) {
    float4 v = A4[i];
    ((float4*)&sA[i >> 5][0])[i & 31] = v;
  }
  __syncthreads();
  const int row = t >> 3, h = t & 7;
  float acc = 0.f;
  #pragma unroll
  for (int c4 = 0; c4 < 32; ++c4) {
    float4 a = ((const float4*)&sA[row][0])[c4];
    float4 w = ((const float4*)&sW[h][0])[c4];
    acc = fmaf(a.x, w.x, acc); acc = fmaf(a.y, w.y, acc);
    acc = fmaf(a.z, w.z, acc); acc = fmaf(a.w, w.w, acc);
  }
  out[(r0 + row) * 8 + h] = acc;
}

// same GEMM but writes fp16 into interleaved level-0 slot: lvl[row*72 + h]
__global__ __launch_bounds__(256) void k_gemm128x8h(const float* __restrict__ A,
                                                    const float* __restrict__ W,
                                                    __half* __restrict__ lvl) {
  __shared__ float sA[32][132];
  __shared__ float sW[8][132];
  const int t = threadIdx.x;
  for (int i = t; i < 1024; i += 256) sW[i & 7][i >> 3] = W[i];
  const long long r0 = (long long)blockIdx.x * 32;
  const float4* A4 = (const float4*)(A + r0 * 128);
  for (int i = t; i < 1024; i += 256) {
    float4 v = A4[i];
    ((float4*)&sA[i >> 5][0])[i & 31] = v;
  }
  __syncthreads();
  const int row = t >> 3, h = t & 7;
  float acc = 0.f;
  #pragma unroll
  for (int c4 = 0; c4 < 32; ++c4) {
    float4 a = ((const float4*)&sA[row][0])[c4];
    float4 w = ((const float4*)&sW[h][0])[c4];
    acc = fmaf(a.x, w.x, acc); acc = fmaf(a.y, w.y, acc);
    acc = fmaf(a.z, w.z, acc); acc = fmaf(a.w, w.w, acc);
  }
  lvl[(r0 + row) * ROW_H + h] = __float2half(acc);
}

// ---------------- generic CSR build: histogram, 2-level scan, scatter ----------------
__global__ __launch_bounds__(256) void k_hist(const int* __restrict__ idx, int n,
                                              int* __restrict__ cnt) {
  int e = blockIdx.x * 256 + threadIdx.x;
  if (e < n) atomicAdd(&cnt[idx[e]], 1);
}

__global__ __launch_bounds__(256) void k_scan_a(const int* __restrict__ cnt, int n,
                                                int* __restrict__ bsum) {
  __shared__ int sd[256];
  int t = threadIdx.x;
  int i0 = blockIdx.x * 1024 + t * 4;
  int s = 0;
  #pragma unroll
  for (int k = 0; k < 4; ++k) if (i0 + k < n) s += cnt[i0 + k];
  sd[t] = s; __syncthreads();
  for (int o = 128; o > 0; o >>= 1) {
    if (t < o) sd[t] += sd[t + o];
    __syncthreads();
  }
  if (t == 0) bsum[blockIdx.x] = sd[0];
}

__global__ __launch_bounds__(512) void k_scan_b(int* __restrict__ bsum, int nblk) {
  __shared__ int sd[512];
  int t = threadIdx.x;
  int v = (t < nblk) ? bsum[t] : 0;
  sd[t] = v; __syncthreads();
  for (int o = 1; o < 512; o <<= 1) {
    int u = (t >= o) ? sd[t - o] : 0;
    __syncthreads();
    sd[t] += u;
    __syncthreads();
  }
  int incl = sd[t];
  if (t < nblk) bsum[t] = incl - v;          // exclusive
  if (t == nblk - 1) bsum[nblk] = incl;      // total
}

__global__ __launch_bounds__(256) void k_scan_c(const int* __restrict__ cnt, int n,
                                                const int* __restrict__ bsum, int nblk,
                                                int* __restrict__ off,
                                                int* __restrict__ cursor) {
  __shared__ int sd[256];
  int t = threadIdx.x, blk = blockIdx.x;
  int i0 = blk * 1024 + t * 4;
  int c0 = (i0 + 0 < n) ? cnt[i0 + 0] : 0;
  int c1 = (i0 + 1 < n) ? cnt[i0 + 1] : 0;
  int c2 = (i0 + 2 < n) ? cnt[i0 + 2] : 0;
  int c3 = (i0 + 3 < n) ? cnt[i0 + 3] : 0;
  int tsum = c0 + c1 + c2 + c3;
  sd[t] = tsum; __syncthreads();
  for (int o = 1; o < 256; o <<= 1) {
    int u = (t >= o) ? sd[t - o] : 0;
    __syncthreads();
    sd[t] += u;
    __syncthreads();
  }
  int base = bsum[blk] + sd[t] - tsum;
  if (i0 + 0 < n) { off[i0 + 0] = base; cursor[i0 + 0] = base; }
  base += c0;
  if (i0 + 1 < n) { off[i0 + 1] = base; cursor[i0 + 1] = base; }
  base += c1;
  if (i0 + 2 < n) { off[i0 + 2] = base; cursor[i0 + 2] = base; }
  base += c2;
  if (i0 + 3 < n) { off[i0 + 3] = base; cursor[i0 + 3] = base; }
  if (blk == 0 && t == 0) off[n] = bsum[nblk];
}

__global__ __launch_bounds__(256) void k_scatter(const int* __restrict__ idx, int n,
                                                 int* __restrict__ cursor,
                                                 int* __restrict__ perm) {
  int e = blockIdx.x * 256 + threadIdx.x;
  if (e >= n) return;
  int pos = atomicAdd(&cursor[idx[e]], 1);
  perm[pos] = e;
}

// ---------------- segment max + 1/sum(exp) via CSR (no atomics) ----------------
__global__ __launch_bounds__(256) void k_seg_ms(const float* __restrict__ tpk,
                                                const int* __restrict__ perm,
                                                const int* __restrict__ off,
                                                int nseg,
                                                float* __restrict__ m_out,
                                                float* __restrict__ rs_out) {
  int gid = blockIdx.x * 256 + threadIdx.x;
  int d = gid >> 3, h = gid & 7;
  if (d >= nseg) return;
  int p0 = off[d], p1 = off[d + 1];
  float m = -3.402823466e38f;
  for (int p = p0; p < p1; ++p)
    m = fmaxf(m, tpk[(long long)perm[p] * 8 + h]);
  float s = 0.f;
  for (int p = p0; p < p1; ++p)
    s += expf(tpk[(long long)perm[p] * 8 + h] - m);
  m_out[(long long)d * 8 + h] = m;
  rs_out[(long long)d * 8 + h] = 1.0f / s;
}

// ---------------- alpha = exp(tpk - m[seg]) * rs[seg]  (in place, coalesced) ----------------
__global__ __launch_bounds__(256) void k_alpha(float* __restrict__ tpk,
                                               const int* __restrict__ seg,
                                               const float* __restrict__ m,
                                               const float* __restrict__ rs) {
  int i = blockIdx.x * 256 + threadIdx.x;
  if (i >= N_IJKL) return;
  int sg = seg[i];
  float4* r = (float4*)(tpk + (long long)i * 8);
  const float4* mp = (const float4*)(m + (long long)sg * 8);
  const float4* rp = (const float4*)(rs + (long long)sg * 8);
  float4 a = r[0], b = r[1];
  float4 m0 = mp[0], m1 = mp[1];
  float4 q0 = rp[0], q1 = rp[1];
  a.x = expf(a.x - m0.x) * q0.x; a.y = expf(a.y - m0.y) * q0.y;
  a.z = expf(a.z - m0.z) * q0.z; a.w = expf(a.w - m0.w) * q0.w;
  b.x = expf(b.x - m1.x) * q1.x; b.y = expf(b.y - m1.y) * q1.y;
  b.z = expf(b.z - m1.z) * q1.z; b.w = expf(b.w - m1.w) * q1.w;
  r[0] = a; r[1] = b;
}

// kerp[pos] = (half)alpha[aidx[perm[pos]]]
__global__ __launch_bounds__(256) void k_gatherp(const float* __restrict__ alpha,
                                                 const int* __restrict__ perm,
                                                 const int* __restrict__ aidx,
                                                 __half* __restrict__ kerp) {
  int pos = blockIdx.x * 256 + threadIdx.x;
  if (pos >= N_UIJKL) return;
  int e = perm[pos];
  const float4* s4 = (const float4*)(alpha + (long long)aidx[e] * 8);
  float4 a = s4[0], b = s4[1];
  __half2* d2 = (__half2*)(kerp + (long long)pos * 8);
  d2[0] = __floats2half2_rn(a.x, a.y);
  d2[1] = __floats2half2_rn(a.z, a.w);
  d2[2] = __floats2half2_rn(b.x, b.y);
  d2[3] = __floats2half2_rn(b.z, b.w);
}

__global__ __launch_bounds__(256) void k_srcp(const int* __restrict__ perm,
                                              const int* __restrict__ gsrc,
                                              int* __restrict__ srcp) {
  int pos = blockIdx.x * 256 + threadIdx.x;
  if (pos >= N_UIJKL) return;
  srcp[pos] = gsrc[perm[pos]];
}

// ---------------- conv (CSR, fp16 in/out, f32 accum): 4 lanes (half2) per dst ----------------
__global__ __launch_bounds__(256) void k_conv(const __half* __restrict__ kerp,
                                              const int* __restrict__ srcp,
                                              const int* __restrict__ off,
                                              __half* __restrict__ lvl,
                                              int tin) {
  int gid = blockIdx.x * 256 + threadIdx.x;
  int d = gid >> 2, h2 = (gid & 3) * 2;
  if (d >= N_UIJK) return;
  int p0 = off[d], p1 = off[d + 1];
  const __half* lin = lvl + tin * 8 + h2;
  float ax = 0.f, ay = 0.f;
  for (int p = p0; p < p1; ++p) {
    int src = srcp[p];
    __half2 kv = *(const __half2*)(kerp + (long long)p * 8 + h2);
    __half2 xv = *(const __half2*)(lin + (long long)src * ROW_H);
    float2 kf = __half22float2(kv), xf = __half22float2(xv);
    ax = fmaf(kf.x, xf.x, ax);
    ay = fmaf(kf.y, xf.y, ay);
  }
  *(__half2*)(lvl + (long long)d * ROW_H + (tin + 1) * 8 + h2) = __floats2half2_rn(ax, ay);
}

// ---------------- fused MLP: 1 row/thread, fp16 weights in LDS, v_fma_mix ----------------
__global__ __launch_bounds__(256) void k_mlp(const __half* __restrict__ lvl,
                                             const float* __restrict__ prop,
                                             const float* __restrict__ W1,
                                             const float* __restrict__ b1,
                                             const float* __restrict__ W2,
                                             const float* __restrict__ b2,
                                             float* __restrict__ outp) {
  __shared__ __align__(16) __half w1s[72 * 72];    // 10368 B
  __shared__ __align__(16) __half w2s[72 * 128];   // 18432 B
  const int t = threadIdx.x;
  for (int i = t; i < 72 * 72; i += 256) w1s[i] = __float2half(W1[i]);
  for (int i = t; i < 72 * 128; i += 256) w2s[i] = __float2half(W2[i]);
  __syncthreads();

  const long long r = (long long)blockIdx.x * 256 + t;
  if (r >= N_UIJK) return;

  float h[72];
  #pragma unroll
  for (int j = 0; j < 72; ++j) h[j] = b1[j];

  // phase 1: x is one contiguous 144B fp16 row; one float4 = one level (8 halves)
  const float4* xp = (const float4*)(lvl + r * ROW_H);
  #pragma unroll 3
  for (int t9 = 0; t9 < 9; ++t9) {
    float4 xr = xp[t9];
    const __half* hx = (const __half*)&xr;
    #pragma unroll
    for (int k = 0; k < 8; ++k) {
      float xv = __half2float(hx[k]);
      const float4* wv4 = (const float4*)(w1s + (t9 * 8 + k) * 72);
      #pragma unroll
      for (int q = 0; q < 9; ++q) {
        float4 wq = wv4[q];                 // ds_read_b128 (broadcast, 8 weights)
        const __half* w8 = (const __half*)&wq;
        #pragma unroll
        for (int e = 0; e < 8; ++e)
          h[q * 8 + e] = fmaf(__half2float(w8[e]), xv, h[q * 8 + e]);  // v_fma_mix
      }
    }
  }
  // exact GELU
  #pragma unroll
  for (int j = 0; j < 72; ++j) {
    float v = h[j];
    h[j] = 0.5f * v * (1.0f + erff(v * 0.70710678118654752f));
  }
  // phase 2: out = h @ W2 + b2 + prop, 16-col chunks; prop loaded at top of each chunk
  const float4* pr = (const float4*)(prop + r * 128);
  float4* po = (float4*)(outp + r * 128);
  #pragma unroll 1
  for (int ch = 0; ch < 8; ++ch) {
    float4 pv0 = pr[ch * 4 + 0], pv1 = pr[ch * 4 + 1];
    float4 pv2 = pr[ch * 4 + 2], pv3 = pr[ch * 4 + 3];
    float o[16];
    #pragma unroll
    for (int k = 0; k < 16; ++k) o[k] = b2[ch * 16 + k];
    #pragma unroll
    for (int j = 0; j < 72; ++j) {
      float hv = h[j];
      const float4* w2v = (const float4*)(w2s + j * 128 + ch * 16);
      float4 wa = w2v[0], wb = w2v[1];
      const __half* w8a = (const __half*)&wa;
      const __half* w8b = (const __half*)&wb;
      #pragma unroll
      for (int e = 0; e < 8; ++e) o[e] = fmaf(__half2float(w8a[e]), hv, o[e]);
      #pragma unroll
      for (int e = 0; e < 8; ++e) o[8 + e] = fmaf(__half2float(w8b[e]), hv, o[8 + e]);
    }
    po[ch * 4 + 0] = make_float4(o[0] + pv0.x, o[1] + pv0.y, o[2] + pv0.z, o[3] + pv0.w);
    po[ch * 4 + 1] = make_float4(o[4] + pv1.x, o[5] + pv1.y, o[6] + pv1.z, o[7] + pv1.w);
    po[ch * 4 + 2] = make_float4(o[8] + pv2.x, o[9] + pv2.y, o[10] + pv2.z, o[11] + pv2.w);
    po[ch * 4 + 3] = make_float4(o[12] + pv3.x, o[13] + pv3.y, o[14] + pv3.z, o[15] + pv3.w);
  }
}

extern "C" void kernel_launch(void* const* d_in, const int* in_sizes, int n_in,
                              void* d_out, int out_size, void* d_ws, size_t ws_size,
                              hipStream_t stream) {
  const float* prop   = (const float*)d_in[0];
  const float* stereo = (const float*)d_in[1];
  const float* Wv     = (const float*)d_in[2];
  const float* Wk     = (const float*)d_in[3];
  const float* W1     = (const float*)d_in[4];
  const float* b1     = (const float*)d_in[5];
  const float* W2     = (const float*)d_in[6];
  const float* b2     = (const float*)d_in[7];
  const int* g_jkl    = (const int*)d_in[8];
  const int* g_U_ijkl = (const int*)d_in[9];
  const int* g_U_Uijk = (const int*)d_in[10];
  const int* g_U_ujkl = (const int*)d_in[11];

  float* ws    = (float*)d_ws;
  // layout (float-offset units):
  //   tpk/alpha [0,8e6) f32  -> later srcp [0,2e6) int
  //   cnt [8.0e6,8.6e6) | off [8.6e6,9.2e6) | cursor [9.2e6,9.8e6) | bsum [9.8e6,+600)
  //   perm [10e6,12e6) | m [12e6,14e6) | rs [14e6,16e6)
  //   kerp fp16 [16e6,24e6) (16M halves) | lvl fp16 [24e6,42e6) (36M halves, [row][72])
  float* tpk   = ws;
  int* cnt     = (int*)(ws + 8000000);
  int* off     = (int*)(ws + 8600000);
  int* cursor  = (int*)(ws + 9200000);
  int* bsum    = (int*)(ws + 9800000);
  int* perm    = (int*)(ws + 10000000);
  float* m     = ws + 12000000;
  float* rs    = ws + 14000000;
  __half* kerp = (__half*)(ws + 16000000);
  __half* lvl  = (__half*)(ws + 24000000);
  int* srcp    = (int*)ws;

  k_gemm128x8 <<<N_IJKL / 32, 256, 0, stream>>>(stereo, Wk, tpk);
  k_gemm128x8h<<<N_UIJK / 32, 256, 0, stream>>>(prop, Wv, lvl);

  // ---- CSR2: 1M ijkl edges -> 250k jkl segments; atomic-free segment softmax
  const int nb2 = (N_IJK + 1023) / 1024;
  hipMemsetAsync(cnt, 0, N_IJK * sizeof(int), stream);
  k_hist   <<<(N_IJKL + 255) / 256, 256, 0, stream>>>(g_jkl, N_IJKL, cnt);
  k_scan_a <<<nb2, 256, 0, stream>>>(cnt, N_IJK, bsum);
  k_scan_b <<<1, 512, 0, stream>>>(bsum, nb2);
  k_scan_c <<<nb2, 256, 0, stream>>>(cnt, N_IJK, bsum, nb2, off, cursor);
  k_scatter<<<(N_IJKL + 255) / 256, 256, 0, stream>>>(g_jkl, N_IJKL, cursor, perm);

  k_seg_ms <<<(N_IJK * 8 + 255) / 256, 256, 0, stream>>>(tpk, perm, off, N_IJK, m, rs);
  k_alpha  <<<(N_IJKL + 255) / 256, 256, 0, stream>>>(tpk, g_jkl, m, rs);

  // ---- CSR1: 2M Uijkl edges -> 500k Uijk destinations
  const int nb1 = (N_UIJK + 1023) / 1024;
  hipMemsetAsync(cnt, 0, N_UIJK * sizeof(int), stream);
  k_hist   <<<(N_UIJKL + 255) / 256, 256, 0, stream>>>(g_U_ujkl, N_UIJKL, cnt);
  k_scan_a <<<nb1, 256, 0, stream>>>(cnt, N_UIJK, bsum);
  k_scan_b <<<1, 512, 0, stream>>>(bsum, nb1);
  k_scan_c <<<nb1, 256, 0, stream>>>(cnt, N_UIJK, bsum, nb1, off, cursor);
  k_scatter<<<(N_UIJKL + 255) / 256, 256, 0, stream>>>(g_U_ujkl, N_UIJKL, cursor, perm);

  k_gatherp<<<(N_UIJKL + 255) / 256, 256, 0, stream>>>(tpk, perm, g_U_ijkl, kerp);
  k_srcp   <<<(N_UIJKL + 255) / 256, 256, 0, stream>>>(perm, g_U_Uijk, srcp);

  for (int t = 0; t < 8; ++t) {
    k_conv<<<(N_UIJK * 4 + 255) / 256, 256, 0, stream>>>(kerp, srcp, off, lvl, t);
  }

  k_mlp<<<(N_UIJK + 255) / 256, 256, 0, stream>>>(lvl, prop, W1, b1, W2, b2, (float*)d_out);
}

// Round 8
// 1417.631 us; speedup vs baseline: 1.1495x; 1.1495x over previous
//
#include <hip/hip_runtime.h>
#include <hip/hip_fp16.h>

#define N_IJKL   1000000
#define N_UIJK   500000
#define N_IJK    250000
#define N_UIJKL  2000000
#define ROW_H    72        // halves per interleaved level row

typedef _Float16 half8 __attribute__((ext_vector_type(8)));
typedef float f32x4 __attribute__((ext_vector_type(4)));

// ---------------- tall-skinny GEMM: A[N,128] @ W[128,8] -> out[N,8] (f32 out) ----------------
__global__ __launch_bounds__(256) void k_gemm128x8(const float* __restrict__ A,
                                                   const float* __restrict__ W,
                                                   float* __restrict__ out) {
  __shared__ float sA[32][132];
  __shared__ float sW[8][132];
  const int t = threadIdx.x;
  for (int i = t; i < 1024; i += 256) sW[i & 7][i >> 3] = W[i];
  const long long r0 = (long long)blockIdx.x * 32;
  const float4* A4 = (const float4*)(A + r0 * 128);
  for (int i = t; i < 1024; i += 256) {
    float4 v = A4[i];
    ((float4*)&sA[i >> 5][0])[i & 31] = v;
  }
  __syncthreads();
  const int row = t >> 3, h = t & 7;
  float acc = 0.f;
  #pragma unroll
  for (int c4 = 0; c4 < 32; ++c4) {
    float4 a = ((const float4*)&sA[row][0])[c4];
    float4 w = ((const float4*)&sW[h][0])[c4];
    acc = fmaf(a.x, w.x, acc); acc = fmaf(a.y, w.y, acc);
    acc = fmaf(a.z, w.z, acc); acc = fmaf(a.w, w.w, acc);
  }
  out[(r0 + row) * 8 + h] = acc;
}

// same GEMM but writes fp16 into interleaved level-0 slot: lvl[row*72 + h]
__global__ __launch_bounds__(256) void k_gemm128x8h(const float* __restrict__ A,
                                                    const float* __restrict__ W,
                                                    __half* __restrict__ lvl) {
  __shared__ float sA[32][132];
  __shared__ float sW[8][132];
  const int t = threadIdx.x;
  for (int i = t; i < 1024; i += 256) sW[i & 7][i >> 3] = W[i];
  const long long r0 = (long long)blockIdx.x * 32;
  const float4* A4 = (const float4*)(A + r0 * 128);
  for (int i = t; i < 1024; i += 256) {
    float4 v = A4[i];
    ((float4*)&sA[i >> 5][0])[i & 31] = v;
  }
  __syncthreads();
  const int row = t >> 3, h = t & 7;
  float acc = 0.f;
  #pragma unroll
  for (int c4 = 0; c4 < 32; ++c4) {
    float4 a = ((const float4*)&sA[row][0])[c4];
    float4 w = ((const float4*)&sW[h][0])[c4];
    acc = fmaf(a.x, w.x, acc); acc = fmaf(a.y, w.y, acc);
    acc = fmaf(a.z, w.z, acc); acc = fmaf(a.w, w.w, acc);
  }
  lvl[(r0 + row) * ROW_H + h] = __float2half(acc);
}

// ---------------- generic CSR build: histogram, 2-level scan, scatter ----------------
__global__ __launch_bounds__(256) void k_hist(const int* __restrict__ idx, int n,
                                              int* __restrict__ cnt) {
  int e = blockIdx.x * 256 + threadIdx.x;
  if (e < n) atomicAdd(&cnt[idx[e]], 1);
}

__global__ __launch_bounds__(256) void k_scan_a(const int* __restrict__ cnt, int n,
                                                int* __restrict__ bsum) {
  __shared__ int sd[256];
  int t = threadIdx.x;
  int i0 = blockIdx.x * 1024 + t * 4;
  int s = 0;
  #pragma unroll
  for (int k = 0; k < 4; ++k) if (i0 + k < n) s += cnt[i0 + k];
  sd[t] = s; __syncthreads();
  for (int o = 128; o > 0; o >>= 1) {
    if (t < o) sd[t] += sd[t + o];
    __syncthreads();
  }
  if (t == 0) bsum[blockIdx.x] = sd[0];
}

__global__ __launch_bounds__(512) void k_scan_b(int* __restrict__ bsum, int nblk) {
  __shared__ int sd[512];
  int t = threadIdx.x;
  int v = (t < nblk) ? bsum[t] : 0;
  sd[t] = v; __syncthreads();
  for (int o = 1; o < 512; o <<= 1) {
    int u = (t >= o) ? sd[t - o] : 0;
    __syncthreads();
    sd[t] += u;
    __syncthreads();
  }
  int incl = sd[t];
  if (t < nblk) bsum[t] = incl - v;          // exclusive
  if (t == nblk - 1) bsum[nblk] = incl;      // total
}

__global__ __launch_bounds__(256) void k_scan_c(const int* __restrict__ cnt, int n,
                                                const int* __restrict__ bsum, int nblk,
                                                int* __restrict__ off,
                                                int* __restrict__ cursor) {
  __shared__ int sd[256];
  int t = threadIdx.x, blk = blockIdx.x;
  int i0 = blk * 1024 + t * 4;
  int c0 = (i0 + 0 < n) ? cnt[i0 + 0] : 0;
  int c1 = (i0 + 1 < n) ? cnt[i0 + 1] : 0;
  int c2 = (i0 + 2 < n) ? cnt[i0 + 2] : 0;
  int c3 = (i0 + 3 < n) ? cnt[i0 + 3] : 0;
  int tsum = c0 + c1 + c2 + c3;
  sd[t] = tsum; __syncthreads();
  for (int o = 1; o < 256; o <<= 1) {
    int u = (t >= o) ? sd[t - o] : 0;
    __syncthreads();
    sd[t] += u;
    __syncthreads();
  }
  int base = bsum[blk] + sd[t] - tsum;
  if (i0 + 0 < n) { off[i0 + 0] = base; cursor[i0 + 0] = base; }
  base += c0;
  if (i0 + 1 < n) { off[i0 + 1] = base; cursor[i0 + 1] = base; }
  base += c1;
  if (i0 + 2 < n) { off[i0 + 2] = base; cursor[i0 + 2] = base; }
  base += c2;
  if (i0 + 3 < n) { off[i0 + 3] = base; cursor[i0 + 3] = base; }
  if (blk == 0 && t == 0) off[n] = bsum[nblk];
}

__global__ __launch_bounds__(256) void k_scatter(const int* __restrict__ idx, int n,
                                                 int* __restrict__ cursor,
                                                 int* __restrict__ perm) {
  int e = blockIdx.x * 256 + threadIdx.x;
  if (e >= n) return;
  int pos = atomicAdd(&cursor[idx[e]], 1);
  perm[pos] = e;
}

// ---------------- segment max + 1/sum(exp) via CSR (no atomics) ----------------
__global__ __launch_bounds__(256) void k_seg_ms(const float* __restrict__ tpk,
                                                const int* __restrict__ perm,
                                                const int* __restrict__ off,
                                                int nseg,
                                                float* __restrict__ m_out,
                                                float* __restrict__ rs_out) {
  int gid = blockIdx.x * 256 + threadIdx.x;
  int d = gid >> 3, h = gid & 7;
  if (d >= nseg) return;
  int p0 = off[d], p1 = off[d + 1];
  float m = -3.402823466e38f;
  for (int p = p0; p < p1; ++p)
    m = fmaxf(m, tpk[(long long)perm[p] * 8 + h]);
  float s = 0.f;
  for (int p = p0; p < p1; ++p)
    s += expf(tpk[(long long)perm[p] * 8 + h] - m);
  m_out[(long long)d * 8 + h] = m;
  rs_out[(long long)d * 8 + h] = 1.0f / s;
}

// ---------------- alpha = exp(tpk - m[seg]) * rs[seg]  (in place, coalesced) ----------------
__global__ __launch_bounds__(256) void k_alpha(float* __restrict__ tpk,
                                               const int* __restrict__ seg,
                                               const float* __restrict__ m,
                                               const float* __restrict__ rs) {
  int i = blockIdx.x * 256 + threadIdx.x;
  if (i >= N_IJKL) return;
  int sg = seg[i];
  float4* r = (float4*)(tpk + (long long)i * 8);
  const float4* mp = (const float4*)(m + (long long)sg * 8);
  const float4* rp = (const float4*)(rs + (long long)sg * 8);
  float4 a = r[0], b = r[1];
  float4 m0 = mp[0], m1 = mp[1];
  float4 q0 = rp[0], q1 = rp[1];
  a.x = expf(a.x - m0.x) * q0.x; a.y = expf(a.y - m0.y) * q0.y;
  a.z = expf(a.z - m0.z) * q0.z; a.w = expf(a.w - m0.w) * q0.w;
  b.x = expf(b.x - m1.x) * q1.x; b.y = expf(b.y - m1.y) * q1.y;
  b.z = expf(b.z - m1.z) * q1.z; b.w = expf(b.w - m1.w) * q1.w;
  r[0] = a; r[1] = b;
}

// kerp[pos] = (half)alpha[aidx[perm[pos]]]
__global__ __launch_bounds__(256) void k_gatherp(const float* __restrict__ alpha,
                                                 const int* __restrict__ perm,
                                                 const int* __restrict__ aidx,
                                                 __half* __restrict__ kerp) {
  int pos = blockIdx.x * 256 + threadIdx.x;
  if (pos >= N_UIJKL) return;
  int e = perm[pos];
  const float4* s4 = (const float4*)(alpha + (long long)aidx[e] * 8);
  float4 a = s4[0], b = s4[1];
  __half2* d2 = (__half2*)(kerp + (long long)pos * 8);
  d2[0] = __floats2half2_rn(a.x, a.y);
  d2[1] = __floats2half2_rn(a.z, a.w);
  d2[2] = __floats2half2_rn(b.x, b.y);
  d2[3] = __floats2half2_rn(b.z, b.w);
}

__global__ __launch_bounds__(256) void k_srcp(const int* __restrict__ perm,
                                              const int* __restrict__ gsrc,
                                              int* __restrict__ srcp) {
  int pos = blockIdx.x * 256 + threadIdx.x;
  if (pos >= N_UIJKL) return;
  srcp[pos] = gsrc[perm[pos]];
}

// ---------------- conv (CSR, fp16 in/out, f32 accum): 4 lanes (half2) per dst ----------------
__global__ __launch_bounds__(256) void k_conv(const __half* __restrict__ kerp,
                                              const int* __restrict__ srcp,
                                              const int* __restrict__ off,
                                              __half* __restrict__ lvl,
                                              int tin) {
  int gid = blockIdx.x * 256 + threadIdx.x;
  int d = gid >> 2, h2 = (gid & 3) * 2;
  if (d >= N_UIJK) return;
  int p0 = off[d], p1 = off[d + 1];
  const __half* lin = lvl + tin * 8 + h2;
  float ax = 0.f, ay = 0.f;
  for (int p = p0; p < p1; ++p) {
    int src = srcp[p];
    __half2 kv = *(const __half2*)(kerp + (long long)p * 8 + h2);
    __half2 xv = *(const __half2*)(lin + (long long)src * ROW_H);
    float2 kf = __half22float2(kv), xf = __half22float2(xv);
    ax = fmaf(kf.x, xf.x, ax);
    ay = fmaf(kf.y, xf.y, ay);
  }
  *(__half2*)(lvl + (long long)d * ROW_H + (tin + 1) * 8 + h2) = __floats2half2_rn(ax, ay);
}

// ---------------- pack W1/W2 (f32) into MFMA B-fragment fp16 buffers, K padded to 96 ----------------
// B-frag layout (16x16x32): lane l holds col n = l&15, k = (l>>4)*8 + i (i=0..7)
// w1b[((kk*5 + nt)*64 + l)*8 + i],  w2b[((kk*8 + nt)*64 + l)*8 + i]
__global__ __launch_bounds__(256) void k_pack(const float* __restrict__ W1,
                                              const float* __restrict__ W2,
                                              _Float16* __restrict__ w1b,
                                              _Float16* __restrict__ w2b) {
  int t = blockIdx.x * 256 + threadIdx.x;
  if (t < 7680) {   // 3*5*64*8
    int i = t & 7, l = (t >> 3) & 63;
    int nt = (t % 2560) / 512, kk = t / 2560;
    int k = kk * 32 + (l >> 4) * 8 + i, n = nt * 16 + (l & 15);
    w1b[t] = (k < 72 && n < 72) ? (_Float16)W1[k * 72 + n] : (_Float16)0.f;
  }
  if (t < 12288) {  // 3*8*64*8
    int i = t & 7, l = (t >> 3) & 63;
    int nt = (t % 4096) / 512, kk = t / 4096;
    int k = kk * 32 + (l >> 4) * 8 + i, n = nt * 16 + (l & 15);
    w2b[t] = (k < 72) ? (_Float16)W2[k * 128 + n] : (_Float16)0.f;
  }
}

// ---------------- MFMA MLP: 4 waves x 16 rows; H transposed through LDS ----------------
__global__ __launch_bounds__(256) void k_mlp(const __half* __restrict__ lvl,
                                             const float* __restrict__ prop,
                                             const half8* __restrict__ w1b,
                                             const half8* __restrict__ w2b,
                                             const float* __restrict__ b1,
                                             const float* __restrict__ b2,
                                             float* __restrict__ outp) {
  __shared__ __align__(16) _Float16 hs[4][16 * 104];   // per-wave 16x96 H tile, pitch 104
  const int t = threadIdx.x;
  const int wid = t >> 6, l = t & 63;
  const int lr = l & 15;     // A-row / B-col / C-col
  const int lg = l >> 4;     // k-group / C-row-group
  const long long r0 = (long long)blockIdx.x * 64 + wid * 16;

  // ---- phase 1: H = X @ W1  (X: lvl fp16 rows, A-frag direct from global)
  f32x4 acc1[5];
  #pragma unroll
  for (int nt = 0; nt < 5; ++nt) acc1[nt] = (f32x4){0.f, 0.f, 0.f, 0.f};
  #pragma unroll
  for (int kk = 0; kk < 3; ++kk) {
    int k0 = kk * 32 + lg * 8;
    half8 af = {};
    long long r = r0 + lr;
    if (k0 < 72 && r < N_UIJK)
      af = *(const half8*)((const _Float16*)lvl + r * ROW_H + k0);
    #pragma unroll
    for (int nt = 0; nt < 5; ++nt) {
      half8 bf = w1b[(kk * 5 + nt) * 64 + l];
      acc1[nt] = __builtin_amdgcn_mfma_f32_16x16x32_f16(af, bf, acc1[nt], 0, 0, 0);
    }
  }
  // ---- bias + exact GELU, store H tile to LDS (C layout: col=lr, row=lg*4+reg)
  _Float16* hw = &hs[wid][0];
  #pragma unroll
  for (int nt = 0; nt < 5; ++nt) {
    int col = nt * 16 + lr;
    float bv = (col < 72) ? b1[col] : 0.f;
    #pragma unroll
    for (int reg = 0; reg < 4; ++reg) {
      int row = lg * 4 + reg;
      float v = acc1[nt][reg] + bv;
      v = 0.5f * v * (1.0f + erff(v * 0.70710678118654752f));
      hw[row * 104 + col] = (_Float16)v;
    }
  }
  // zero pad cols 80..95 (16 rows x 16 halves; each lane writes 4 halves)
  {
    int row = l >> 2, c0 = 80 + (l & 3) * 4;
    *(float2*)(hw + row * 104 + c0) = make_float2(0.f, 0.f);
  }
  __syncthreads();

  // ---- phase 2: out = H @ W2 + b2 + prop  (A-frag of H from LDS)
  half8 af2[3];
  #pragma unroll
  for (int kk = 0; kk < 3; ++kk)
    af2[kk] = *(const half8*)(hw + lr * 104 + kk * 32 + lg * 8);
  f32x4 acc2[8];
  #pragma unroll
  for (int nt = 0; nt < 8; ++nt) {
    float bv = b2[nt * 16 + lr];
    acc2[nt] = (f32x4){bv, bv, bv, bv};
  }
  #pragma unroll
  for (int kk = 0; kk < 3; ++kk)
    #pragma unroll
    for (int nt = 0; nt < 8; ++nt)
      acc2[nt] = __builtin_amdgcn_mfma_f32_16x16x32_f16(af2[kk], w2b[(kk * 8 + nt) * 64 + l], acc2[nt], 0, 0, 0);

  // ---- epilogue: + prop residual, direct stores (C layout)
  #pragma unroll
  for (int nt = 0; nt < 8; ++nt) {
    int cidx = nt * 16 + lr;
    #pragma unroll
    for (int reg = 0; reg < 4; ++reg) {
      long long row = r0 + lg * 4 + reg;
      if (row < N_UIJK)
        outp[row * 128 + cidx] = acc2[nt][reg] + prop[row * 128 + cidx];
    }
  }
}

extern "C" void kernel_launch(void* const* d_in, const int* in_sizes, int n_in,
                              void* d_out, int out_size, void* d_ws, size_t ws_size,
                              hipStream_t stream) {
  const float* prop   = (const float*)d_in[0];
  const float* stereo = (const float*)d_in[1];
  const float* Wv     = (const float*)d_in[2];
  const float* Wk     = (const float*)d_in[3];
  const float* W1     = (const float*)d_in[4];
  const float* b1     = (const float*)d_in[5];
  const float* W2     = (const float*)d_in[6];
  const float* b2     = (const float*)d_in[7];
  const int* g_jkl    = (const int*)d_in[8];
  const int* g_U_ijkl = (const int*)d_in[9];
  const int* g_U_Uijk = (const int*)d_in[10];
  const int* g_U_ujkl = (const int*)d_in[11];

  float* ws    = (float*)d_ws;
  // layout (float-offset units):
  //   tpk/alpha [0,8e6) f32  -> later srcp [0,2e6) int
  //   cnt [8.0e6,8.6e6) | off [8.6e6,9.2e6) | cursor [9.2e6,9.8e6) | bsum [9.8e6,+600)
  //   perm [10e6,12e6) | m [12e6,14e6) | rs [14e6,16e6)
  //   kerp fp16 [16e6,24e6) | lvl fp16 [24e6,42e6) (36M halves, [row][72])
  //   w1b [42.1e6,+7680 halves) | w2b [42.2e6,+12288 halves)   <-- PAST lvl end (round-7 bug fix)
  float* tpk   = ws;
  int* cnt     = (int*)(ws + 8000000);
  int* off     = (int*)(ws + 8600000);
  int* cursor  = (int*)(ws + 9200000);
  int* bsum    = (int*)(ws + 9800000);
  int* perm    = (int*)(ws + 10000000);
  float* m     = ws + 12000000;
  float* rs    = ws + 14000000;
  __half* kerp = (__half*)(ws + 16000000);
  __half* lvl  = (__half*)(ws + 24000000);
  _Float16* w1b = (_Float16*)(ws + 42100000);
  _Float16* w2b = (_Float16*)(ws + 42200000);
  int* srcp    = (int*)ws;

  k_gemm128x8 <<<N_IJKL / 32, 256, 0, stream>>>(stereo, Wk, tpk);
  k_gemm128x8h<<<N_UIJK / 32, 256, 0, stream>>>(prop, Wv, lvl);
  k_pack      <<<48, 256, 0, stream>>>(W1, W2, w1b, w2b);

  // ---- CSR2: 1M ijkl edges -> 250k jkl segments; atomic-free segment softmax
  const int nb2 = (N_IJK + 1023) / 1024;
  (void)hipMemsetAsync(cnt, 0, N_IJK * sizeof(int), stream);
  k_hist   <<<(N_IJKL + 255) / 256, 256, 0, stream>>>(g_jkl, N_IJKL, cnt);
  k_scan_a <<<nb2, 256, 0, stream>>>(cnt, N_IJK, bsum);
  k_scan_b <<<1, 512, 0, stream>>>(bsum, nb2);
  k_scan_c <<<nb2, 256, 0, stream>>>(cnt, N_IJK, bsum, nb2, off, cursor);
  k_scatter<<<(N_IJKL + 255) / 256, 256, 0, stream>>>(g_jkl, N_IJKL, cursor, perm);

  k_seg_ms <<<(N_IJK * 8 + 255) / 256, 256, 0, stream>>>(tpk, perm, off, N_IJK, m, rs);
  k_alpha  <<<(N_IJKL + 255) / 256, 256, 0, stream>>>(tpk, g_jkl, m, rs);

  // ---- CSR1: 2M Uijkl edges -> 500k Uijk destinations
  const int nb1 = (N_UIJK + 1023) / 1024;
  (void)hipMemsetAsync(cnt, 0, N_UIJK * sizeof(int), stream);
  k_hist   <<<(N_UIJKL + 255) / 256, 256, 0, stream>>>(g_U_ujkl, N_UIJKL, cnt);
  k_scan_a <<<nb1, 256, 0, stream>>>(cnt, N_UIJK, bsum);
  k_scan_b <<<1, 512, 0, stream>>>(bsum, nb1);
  k_scan_c <<<nb1, 256, 0, stream>>>(cnt, N_UIJK, bsum, nb1, off, cursor);
  k_scatter<<<(N_UIJKL + 255) / 256, 256, 0, stream>>>(g_U_ujkl, N_UIJKL, cursor, perm);

  k_gatherp<<<(N_UIJKL + 255) / 256, 256, 0, stream>>>(tpk, perm, g_U_ijkl, kerp);
  k_srcp   <<<(N_UIJKL + 255) / 256, 256, 0, stream>>>(perm, g_U_Uijk, srcp);

  for (int t = 0; t < 8; ++t) {
    k_conv<<<(N_UIJK * 4 + 255) / 256, 256, 0, stream>>>(kerp, srcp, off, lvl, t);
  }

  k_mlp<<<(N_UIJK + 63) / 64, 256, 0, stream>>>(lvl, prop, (const half8*)w1b, (const half8*)w2b, b1, b2, (float*)d_out);
}

// Round 9
// 1149.007 us; speedup vs baseline: 1.4183x; 1.2338x over previous
//
#include <hip/hip_runtime.h>
#include <hip/hip_fp16.h>

#define N_IJKL   1000000
#define N_UIJK   500000
#define N_IJK    250000
#define N_UIJKL  2000000
#define LVL_H    4000000LL   // halves per level array [500k x 8]

typedef _Float16 half8 __attribute__((ext_vector_type(8)));
typedef float f32x4 __attribute__((ext_vector_type(4)));

// ---------------- tall-skinny GEMM: A[N,128] @ W[128,8] -> out[N,8] (f32 out) ----------------
__global__ __launch_bounds__(256) void k_gemm128x8(const float* __restrict__ A,
                                                   const float* __restrict__ W,
                                                   float* __restrict__ out) {
  __shared__ float sA[32][132];
  __shared__ float sW[8][132];
  const int t = threadIdx.x;
  for (int i = t; i < 1024; i += 256) sW[i & 7][i >> 3] = W[i];
  const long long r0 = (long long)blockIdx.x * 32;
  const float4* A4 = (const float4*)(A + r0 * 128);
  for (int i = t; i < 1024; i += 256) {
    float4 v = A4[i];
    ((float4*)&sA[i >> 5][0])[i & 31] = v;
  }
  __syncthreads();
  const int row = t >> 3, h = t & 7;
  float acc = 0.f;
  #pragma unroll
  for (int c4 = 0; c4 < 32; ++c4) {
    float4 a = ((const float4*)&sA[row][0])[c4];
    float4 w = ((const float4*)&sW[h][0])[c4];
    acc = fmaf(a.x, w.x, acc); acc = fmaf(a.y, w.y, acc);
    acc = fmaf(a.z, w.z, acc); acc = fmaf(a.w, w.w, acc);
  }
  out[(r0 + row) * 8 + h] = acc;
}

// same GEMM, fp16 output into dense level-0 array
__global__ __launch_bounds__(256) void k_gemm128x8h(const float* __restrict__ A,
                                                    const float* __restrict__ W,
                                                    __half* __restrict__ lvl0) {
  __shared__ float sA[32][132];
  __shared__ float sW[8][132];
  const int t = threadIdx.x;
  for (int i = t; i < 1024; i += 256) sW[i & 7][i >> 3] = W[i];
  const long long r0 = (long long)blockIdx.x * 32;
  const float4* A4 = (const float4*)(A + r0 * 128);
  for (int i = t; i < 1024; i += 256) {
    float4 v = A4[i];
    ((float4*)&sA[i >> 5][0])[i & 31] = v;
  }
  __syncthreads();
  const int row = t >> 3, h = t & 7;
  float acc = 0.f;
  #pragma unroll
  for (int c4 = 0; c4 < 32; ++c4) {
    float4 a = ((const float4*)&sA[row][0])[c4];
    float4 w = ((const float4*)&sW[h][0])[c4];
    acc = fmaf(a.x, w.x, acc); acc = fmaf(a.y, w.y, acc);
    acc = fmaf(a.z, w.z, acc); acc = fmaf(a.w, w.w, acc);
  }
  lvl0[(r0 + row) * 8 + h] = __float2half(acc);
}

// ---------------- generic CSR build: histogram, 2-level scan ----------------
__global__ __launch_bounds__(256) void k_hist(const int* __restrict__ idx, int n,
                                              int* __restrict__ cnt) {
  int e = blockIdx.x * 256 + threadIdx.x;
  if (e < n) atomicAdd(&cnt[idx[e]], 1);
}

__global__ __launch_bounds__(256) void k_scan_a(const int* __restrict__ cnt, int n,
                                                int* __restrict__ bsum) {
  __shared__ int sd[256];
  int t = threadIdx.x;
  int i0 = blockIdx.x * 1024 + t * 4;
  int s = 0;
  #pragma unroll
  for (int k = 0; k < 4; ++k) if (i0 + k < n) s += cnt[i0 + k];
  sd[t] = s; __syncthreads();
  for (int o = 128; o > 0; o >>= 1) {
    if (t < o) sd[t] += sd[t + o];
    __syncthreads();
  }
  if (t == 0) bsum[blockIdx.x] = sd[0];
}

__global__ __launch_bounds__(512) void k_scan_b(int* __restrict__ bsum, int nblk) {
  __shared__ int sd[512];
  int t = threadIdx.x;
  int v = (t < nblk) ? bsum[t] : 0;
  sd[t] = v; __syncthreads();
  for (int o = 1; o < 512; o <<= 1) {
    int u = (t >= o) ? sd[t - o] : 0;
    __syncthreads();
    sd[t] += u;
    __syncthreads();
  }
  int incl = sd[t];
  if (t < nblk) bsum[t] = incl - v;          // exclusive
  if (t == nblk - 1) bsum[nblk] = incl;      // total
}

__global__ __launch_bounds__(256) void k_scan_c(const int* __restrict__ cnt, int n,
                                                const int* __restrict__ bsum, int nblk,
                                                int* __restrict__ off,
                                                int* __restrict__ cursor) {
  __shared__ int sd[256];
  int t = threadIdx.x, blk = blockIdx.x;
  int i0 = blk * 1024 + t * 4;
  int c0 = (i0 + 0 < n) ? cnt[i0 + 0] : 0;
  int c1 = (i0 + 1 < n) ? cnt[i0 + 1] : 0;
  int c2 = (i0 + 2 < n) ? cnt[i0 + 2] : 0;
  int c3 = (i0 + 3 < n) ? cnt[i0 + 3] : 0;
  int tsum = c0 + c1 + c2 + c3;
  sd[t] = tsum; __syncthreads();
  for (int o = 1; o < 256; o <<= 1) {
    int u = (t >= o) ? sd[t - o] : 0;
    __syncthreads();
    sd[t] += u;
    __syncthreads();
  }
  int base = bsum[blk] + sd[t] - tsum;
  if (i0 + 0 < n) { off[i0 + 0] = base; cursor[i0 + 0] = base; }
  base += c0;
  if (i0 + 1 < n) { off[i0 + 1] = base; cursor[i0 + 1] = base; }
  base += c1;
  if (i0 + 2 < n) { off[i0 + 2] = base; cursor[i0 + 2] = base; }
  base += c2;
  if (i0 + 3 < n) { off[i0 + 3] = base; cursor[i0 + 3] = base; }
  if (blk == 0 && t == 0) off[n] = bsum[nblk];
}

// ---------------- CSR2 payload scatter: tpkp[pos] = tpk[e] (coalesced read, random write) ----
__global__ __launch_bounds__(256) void k_scat2(const int* __restrict__ seg,
                                               int* __restrict__ cursor,
                                               const float* __restrict__ tpk,
                                               float* __restrict__ tpkp) {
  int e = blockIdx.x * 256 + threadIdx.x;
  if (e >= N_IJKL) return;
  int pos = atomicAdd(&cursor[seg[e]], 1);
  const float4* s4 = (const float4*)(tpk + (long long)e * 8);
  float4* d4 = (float4*)(tpkp + (long long)pos * 8);
  d4[0] = s4[0]; d4[1] = s4[1];
}

// ---------------- segment max + 1/sum(exp), coalesced CSR walk ----------------
__global__ __launch_bounds__(256) void k_seg_ms(const float* __restrict__ tpkp,
                                                const int* __restrict__ off,
                                                int nseg,
                                                float* __restrict__ m_out,
                                                float* __restrict__ rs_out) {
  int gid = blockIdx.x * 256 + threadIdx.x;
  int d = gid >> 3, h = gid & 7;
  if (d >= nseg) return;
  int p0 = off[d], p1 = off[d + 1];
  float m = -3.402823466e38f;
  for (int p = p0; p < p1; ++p)
    m = fmaxf(m, tpkp[(long long)p * 8 + h]);
  float s = 0.f;
  for (int p = p0; p < p1; ++p)
    s += expf(tpkp[(long long)p * 8 + h] - m);
  m_out[(long long)d * 8 + h] = m;
  rs_out[(long long)d * 8 + h] = 1.0f / s;
}

// ---------------- alpha = exp(tpk - m[seg]) * rs[seg]  (in place, coalesced) ----------------
__global__ __launch_bounds__(256) void k_alpha(float* __restrict__ tpk,
                                               const int* __restrict__ seg,
                                               const float* __restrict__ m,
                                               const float* __restrict__ rs) {
  int i = blockIdx.x * 256 + threadIdx.x;
  if (i >= N_IJKL) return;
  int sg = seg[i];
  float4* r = (float4*)(tpk + (long long)i * 8);
  const float4* mp = (const float4*)(m + (long long)sg * 8);
  const float4* rp = (const float4*)(rs + (long long)sg * 8);
  float4 a = r[0], b = r[1];
  float4 m0 = mp[0], m1 = mp[1];
  float4 q0 = rp[0], q1 = rp[1];
  a.x = expf(a.x - m0.x) * q0.x; a.y = expf(a.y - m0.y) * q0.y;
  a.z = expf(a.z - m0.z) * q0.z; a.w = expf(a.w - m0.w) * q0.w;
  b.x = expf(b.x - m1.x) * q1.x; b.y = expf(b.y - m1.y) * q1.y;
  b.z = expf(b.z - m1.z) * q1.z; b.w = expf(b.w - m1.w) * q1.w;
  r[0] = a; r[1] = b;
}

// ---------------- CSR1 payload scatter: kerp[pos] = (half)alpha[aidx[e]], srcp[pos] = gsrc[e] ----
__global__ __launch_bounds__(256) void k_scat1(const int* __restrict__ dst,
                                               const int* __restrict__ aidx,
                                               const int* __restrict__ gsrc,
                                               int* __restrict__ cursor,
                                               const float* __restrict__ alpha,
                                               __half* __restrict__ kerp,
                                               int* __restrict__ srcp) {
  int e = blockIdx.x * 256 + threadIdx.x;
  if (e >= N_UIJKL) return;
  int pos = atomicAdd(&cursor[dst[e]], 1);
  const float4* s4 = (const float4*)(alpha + (long long)aidx[e] * 8);
  float4 a = s4[0], b = s4[1];
  __half2* d2 = (__half2*)(kerp + (long long)pos * 8);
  d2[0] = __floats2half2_rn(a.x, a.y);
  d2[1] = __floats2half2_rn(a.z, a.w);
  d2[2] = __floats2half2_rn(b.x, b.y);
  d2[3] = __floats2half2_rn(b.z, b.w);
  srcp[pos] = gsrc[e];
}

// ---------------- conv (CSR, fp16, dense 8-wide levels): 4 lanes (half2) per dst ----------------
__global__ __launch_bounds__(256) void k_conv(const __half* __restrict__ kerp,
                                              const int* __restrict__ srcp,
                                              const int* __restrict__ off,
                                              const __half* __restrict__ lin,
                                              __half* __restrict__ lout) {
  int gid = blockIdx.x * 256 + threadIdx.x;
  int d = gid >> 2, h2 = (gid & 3) * 2;
  if (d >= N_UIJK) return;
  int p0 = off[d], p1 = off[d + 1];
  float ax = 0.f, ay = 0.f;
  for (int p = p0; p < p1; ++p) {
    int src = srcp[p];
    __half2 kv = *(const __half2*)(kerp + (long long)p * 8 + h2);
    __half2 xv = *(const __half2*)(lin + (long long)src * 8 + h2);
    float2 kf = __half22float2(kv), xf = __half22float2(xv);
    ax = fmaf(kf.x, xf.x, ax);
    ay = fmaf(kf.y, xf.y, ay);
  }
  *(__half2*)(lout + (long long)d * 8 + h2) = __floats2half2_rn(ax, ay);
}

// ---------------- pack W1/W2 (f32) into MFMA B-fragment fp16 buffers, K padded to 96 ----------------
__global__ __launch_bounds__(256) void k_pack(const float* __restrict__ W1,
                                              const float* __restrict__ W2,
                                              _Float16* __restrict__ w1b,
                                              _Float16* __restrict__ w2b) {
  int t = blockIdx.x * 256 + threadIdx.x;
  if (t < 7680) {   // 3*5*64*8
    int i = t & 7, l = (t >> 3) & 63;
    int nt = (t % 2560) / 512, kk = t / 2560;
    int k = kk * 32 + (l >> 4) * 8 + i, n = nt * 16 + (l & 15);
    w1b[t] = (k < 72 && n < 72) ? (_Float16)W1[k * 72 + n] : (_Float16)0.f;
  }
  if (t < 12288) {  // 3*8*64*8
    int i = t & 7, l = (t >> 3) & 63;
    int nt = (t % 4096) / 512, kk = t / 4096;
    int k = kk * 32 + (l >> 4) * 8 + i, n = nt * 16 + (l & 15);
    w2b[t] = (k < 72) ? (_Float16)W2[k * 128 + n] : (_Float16)0.f;
  }
}

// ---------------- MFMA MLP: 4 waves x 16 rows; H through LDS ----------------
__global__ __launch_bounds__(256) void k_mlp(const __half* __restrict__ lvl,
                                             const float* __restrict__ prop,
                                             const half8* __restrict__ w1b,
                                             const half8* __restrict__ w2b,
                                             const float* __restrict__ b1,
                                             const float* __restrict__ b2,
                                             float* __restrict__ outp) {
  __shared__ __align__(16) _Float16 hs[4][16 * 104];
  const int t = threadIdx.x;
  const int wid = t >> 6, l = t & 63;
  const int lr = l & 15;     // A-row / B-col / C-col
  const int lg = l >> 4;     // k-group / C-row-group
  const long long r0 = (long long)blockIdx.x * 64 + wid * 16;

  // ---- phase 1: H = X @ W1 ; A-frag 8 k-values = one dense level row
  f32x4 acc1[5];
  #pragma unroll
  for (int nt = 0; nt < 5; ++nt) acc1[nt] = (f32x4){0.f, 0.f, 0.f, 0.f};
  #pragma unroll
  for (int kk = 0; kk < 3; ++kk) {
    int k0 = kk * 32 + lg * 8;
    half8 af = {};
    long long r = r0 + lr;
    if (k0 < 72 && r < N_UIJK)
      af = *(const half8*)((const _Float16*)lvl + (long long)(k0 >> 3) * LVL_H + r * 8);
    #pragma unroll
    for (int nt = 0; nt < 5; ++nt) {
      half8 bf = w1b[(kk * 5 + nt) * 64 + l];
      acc1[nt] = __builtin_amdgcn_mfma_f32_16x16x32_f16(af, bf, acc1[nt], 0, 0, 0);
    }
  }
  // ---- bias + exact GELU, store H tile to LDS (C layout: col=lr, row=lg*4+reg)
  _Float16* hw = &hs[wid][0];
  #pragma unroll
  for (int nt = 0; nt < 5; ++nt) {
    int col = nt * 16 + lr;
    float bv = (col < 72) ? b1[col] : 0.f;
    #pragma unroll
    for (int reg = 0; reg < 4; ++reg) {
      int row = lg * 4 + reg;
      float v = acc1[nt][reg] + bv;
      v = 0.5f * v * (1.0f + erff(v * 0.70710678118654752f));
      hw[row * 104 + col] = (_Float16)v;
    }
  }
  {
    int row = l >> 2, c0 = 80 + (l & 3) * 4;
    *(float2*)(hw + row * 104 + c0) = make_float2(0.f, 0.f);
  }
  __syncthreads();

  // ---- phase 2: out = H @ W2 + b2 + prop
  half8 af2[3];
  #pragma unroll
  for (int kk = 0; kk < 3; ++kk)
    af2[kk] = *(const half8*)(hw + lr * 104 + kk * 32 + lg * 8);
  f32x4 acc2[8];
  #pragma unroll
  for (int nt = 0; nt < 8; ++nt) {
    float bv = b2[nt * 16 + lr];
    acc2[nt] = (f32x4){bv, bv, bv, bv};
  }
  #pragma unroll
  for (int kk = 0; kk < 3; ++kk)
    #pragma unroll
    for (int nt = 0; nt < 8; ++nt)
      acc2[nt] = __builtin_amdgcn_mfma_f32_16x16x32_f16(af2[kk], w2b[(kk * 8 + nt) * 64 + l], acc2[nt], 0, 0, 0);

  #pragma unroll
  for (int nt = 0; nt < 8; ++nt) {
    int cidx = nt * 16 + lr;
    #pragma unroll
    for (int reg = 0; reg < 4; ++reg) {
      long long row = r0 + lg * 4 + reg;
      if (row < N_UIJK)
        outp[row * 128 + cidx] = acc2[nt][reg] + prop[row * 128 + cidx];
    }
  }
}

extern "C" void kernel_launch(void* const* d_in, const int* in_sizes, int n_in,
                              void* d_out, int out_size, void* d_ws, size_t ws_size,
                              hipStream_t stream) {
  const float* prop   = (const float*)d_in[0];
  const float* stereo = (const float*)d_in[1];
  const float* Wv     = (const float*)d_in[2];
  const float* Wk     = (const float*)d_in[3];
  const float* W1     = (const float*)d_in[4];
  const float* b1     = (const float*)d_in[5];
  const float* W2     = (const float*)d_in[6];
  const float* b2     = (const float*)d_in[7];
  const int* g_jkl    = (const int*)d_in[8];
  const int* g_U_ijkl = (const int*)d_in[9];
  const int* g_U_Uijk = (const int*)d_in[10];
  const int* g_U_ujkl = (const int*)d_in[11];

  float* ws    = (float*)d_ws;
  // layout (float-offset units):
  //   tpk/alpha [0,8e6)
  //   cnt [8.0e6) | off [8.6e6) | cursor [9.2e6) | bsum [9.8e6)   (ints, 600k each)
  //   m [12e6,14e6) | rs [14e6,16e6)
  //   kerp fp16 [16e6,24e6) | lvl fp16 [24e6,42e6) (9 x 4e6-half dense levels)
  //   w1b [42.1e6) | w2b [42.2e6) (halves) | srcp int [42.3e6,44.3e6) | tpkp [44.3e6,52.3e6)
  float* tpk   = ws;
  int* cnt     = (int*)(ws + 8000000);
  int* off     = (int*)(ws + 8600000);
  int* cursor  = (int*)(ws + 9200000);
  int* bsum    = (int*)(ws + 9800000);
  float* m     = ws + 12000000;
  float* rs    = ws + 14000000;
  __half* kerp = (__half*)(ws + 16000000);
  __half* lvl  = (__half*)(ws + 24000000);
  _Float16* w1b = (_Float16*)(ws + 42100000);
  _Float16* w2b = (_Float16*)(ws + 42200000);
  int* srcp    = (int*)(ws + 42300000);
  float* tpkp  = ws + 44300000;

  k_gemm128x8 <<<N_IJKL / 32, 256, 0, stream>>>(stereo, Wk, tpk);
  k_gemm128x8h<<<N_UIJK / 32, 256, 0, stream>>>(prop, Wv, lvl);
  k_pack      <<<48, 256, 0, stream>>>(W1, W2, w1b, w2b);

  // ---- CSR2: 1M ijkl edges -> 250k jkl segments; atomic-free segment softmax
  const int nb2 = (N_IJK + 1023) / 1024;
  (void)hipMemsetAsync(cnt, 0, N_IJK * sizeof(int), stream);
  k_hist   <<<(N_IJKL + 255) / 256, 256, 0, stream>>>(g_jkl, N_IJKL, cnt);
  k_scan_a <<<nb2, 256, 0, stream>>>(cnt, N_IJK, bsum);
  k_scan_b <<<1, 512, 0, stream>>>(bsum, nb2);
  k_scan_c <<<nb2, 256, 0, stream>>>(cnt, N_IJK, bsum, nb2, off, cursor);
  k_scat2  <<<(N_IJKL + 255) / 256, 256, 0, stream>>>(g_jkl, cursor, tpk, tpkp);

  k_seg_ms <<<(N_IJK * 8 + 255) / 256, 256, 0, stream>>>(tpkp, off, N_IJK, m, rs);
  k_alpha  <<<(N_IJKL + 255) / 256, 256, 0, stream>>>(tpk, g_jkl, m, rs);

  // ---- CSR1: 2M Uijkl edges -> 500k Uijk destinations; payload scatter (no perm)
  const int nb1 = (N_UIJK + 1023) / 1024;
  (void)hipMemsetAsync(cnt, 0, N_UIJK * sizeof(int), stream);
  k_hist   <<<(N_UIJKL + 255) / 256, 256, 0, stream>>>(g_U_ujkl, N_UIJKL, cnt);
  k_scan_a <<<nb1, 256, 0, stream>>>(cnt, N_UIJK, bsum);
  k_scan_b <<<1, 512, 0, stream>>>(bsum, nb1);
  k_scan_c <<<nb1, 256, 0, stream>>>(cnt, N_UIJK, bsum, nb1, off, cursor);
  k_scat1  <<<(N_UIJKL + 255) / 256, 256, 0, stream>>>(g_U_ujkl, g_U_ijkl, g_U_Uijk,
                                                       cursor, tpk, kerp, srcp);

  for (int t = 0; t < 8; ++t) {
    k_conv<<<(N_UIJK * 4 + 255) / 256, 256, 0, stream>>>(
        kerp, srcp, off, lvl + t * LVL_H, lvl + (t + 1) * LVL_H);
  }

  k_mlp<<<(N_UIJK + 63) / 64, 256, 0, stream>>>(lvl, prop, (const half8*)w1b, (const half8*)w2b,
                                                b1, b2, (float*)d_out);
}